// Round 10
// baseline (75.050 us; speedup 1.0000x reference)
//
#include <hip/hip_runtime.h>

typedef __attribute__((ext_vector_type(8)))  short short8;
typedef __attribute__((ext_vector_type(16))) float f32x16;

namespace {

__device__ __forceinline__ unsigned short f2bf(float f) {
    unsigned int u = __float_as_uint(f);
    u += 0x7fffu + ((u >> 16) & 1u);     // RNE to bf16
    return (unsigned short)(u >> 16);
}

__device__ __forceinline__ f32x16 zero16() {
    f32x16 z;
#pragma unroll
    for (int r = 0; r < 16; ++r) z[r] = 0.0f;
    return z;
}

// ---------------------------------------------------------------------------
// B3: A-fragments (taps) for mfma_f32_32x32x16_bf16, lane-major coalesced.
// Linear index = ic*512 + (ot*4+kq)*64 + lane. Lane (m=lane&31, h=lane>>5)
// holds 8 bf16: taps q=0..7 (flipped, q==7 zero) of tap-row a = 2*kq+h
// (flipped; a==7 -> all zero) for oc = 32*ot + m. A/B use the same lane->k
// mapping, so any consistent (h,j) fill contracts correctly.
// ---------------------------------------------------------------------------
__global__ void prep_B(const float* __restrict__ ker, uint4* __restrict__ B3) {
    int t    = blockIdx.x * 256 + threadIdx.x;   // 16384 threads
    int lane = t & 63;
    int kq   = (t >> 6) & 3;
    int ot   = (t >> 8) & 1;
    int ic   = t >> 9;
    int m = lane & 31, h = lane >> 5;
    int oc = ot * 32 + m;
    int a  = 2 * kq + h;
    unsigned int d[4] = {0u, 0u, 0u, 0u};
    if (a < 7) {
        const float* row = ker + ((oc * 32 + ic) * 49) + (6 - a) * 7;
        float v[8];
#pragma unroll
        for (int q = 0; q < 7; ++q) v[q] = row[6 - q];
        v[7] = 0.0f;
#pragma unroll
        for (int j = 0; j < 4; ++j)
            d[j] = (unsigned int)f2bf(v[2 * j]) | ((unsigned int)f2bf(v[2 * j + 1]) << 16);
    }
    B3[t] = make_uint4(d[0], d[1], d[2], d[3]);
}

// ---------------------------------------------------------------------------
// Conv: grid 512 = b(8) x y(64), block 512 thr (8 waves) -> 2 blocks/CU.
// Wave w: xh = w&1 (32-px half), icg = w>>1 (8-ic group). Per ic: 8 tap loads,
// 4 img frags, 8 mfma_32x32x16, 32 fabs-adds.
// H (pitch 72, plane stride 504): dword p = pack(bf16 col (p-2)%64, (p-1)%64),
// window rows r=0..6 = img rows (y-2+r)%64. Img frag = STRIDE-2 dwords
// (+0,+2,+4,+6) -> cols x-2..x+5 (consecutive dwords would give overlapping
// pairs - the R9 bug). kq==3 reads row 6 for BOTH halves: h=1 (a=7) lanes get
// real row-6 data times all-zero taps.
// 4-way icg merge: 3 barriers, in-LDS tree aliased on dead H; plain stores.
// ---------------------------------------------------------------------------
__global__ __launch_bounds__(512, 4) void conv_mfma(
    const float* __restrict__ img,          // [8][32][64][64]
    const uint4* __restrict__ B3,           // prepped taps
    float* __restrict__ out)                // [8][64][64][64]
{
    __shared__ unsigned int H[16128];       // 32*504 dwords = 63 KB

    const int bid  = blockIdx.x;            // b*64 + y
    const int y    = bid & 63;
    const int b    = bid >> 6;
    const int tid  = threadIdx.x;
    const int lane = tid & 63;
    const int w    = tid >> 6;              // 8 waves
    const int xh   = w & 1;
    const int icg  = w >> 1;                // 0..3, 8 ic each
    const int n31  = lane & 31;
    const int h    = lane >> 5;

    const float* base = img + (size_t)b * 32 * 4096;

    // ---- stage: wave w owns planes 4w..4w+3, 7 rows each; col = lane ----
    float v[28];
#pragma unroll
    for (int j = 0; j < 28; ++j) {
        const int pl  = 4 * w + j / 7;
        const int row = (y - 2 + (j % 7)) & 63;
        v[j] = base[pl * 4096 + row * 64 + lane];
    }
#pragma unroll
    for (int j = 0; j < 28; ++j) {
        const int pl = 4 * w + j / 7;
        const int r  = j % 7;
        const unsigned int hh = f2bf(v[j]);
        const unsigned int hn = (unsigned int)__shfl((int)hh, (lane + 1) & 63);
        const unsigned int dw = hh | (hn << 16);  // cols (lane, lane+1) -> dword lane+2
        const int idx = pl * 504 + r * 72;
        H[idx + lane + 2] = dw;
        if (lane >= 62) H[idx + lane - 62] = dw;  // wrap left  (p = 0,1)
        if (lane <= 5)  H[idx + lane + 66] = dw;  // wrap right (p = 66..71)
    }
    __syncthreads();

    // ---- compute: 8 ic x (2 ot x 4 kq) ----
    f32x16 acc[2] = {zero16(), zero16()};
    const int xloc = 32 * xh + n31;
    const int hv   = h * 72;

#pragma unroll 2
    for (int ici = 0; ici < 8; ++ici) {
        const int ic = icg * 8 + ici;
        uint4 tf[8];                              // q = ot*4 + kq
#pragma unroll
        for (int q = 0; q < 8; ++q)
            tf[q] = B3[ic * 512 + q * 64 + lane];

        short8 fr[4];
#pragma unroll
        for (int kq = 0; kq < 4; ++kq) {
            const int ad = ic * 504 + ((kq < 3) ? (2 * kq * 72 + hv) : 432) + xloc;
            uint4 t4 = make_uint4(H[ad], H[ad + 2], H[ad + 4], H[ad + 6]);
            fr[kq] = __builtin_bit_cast(short8, t4);
        }
#pragma unroll
        for (int ot = 0; ot < 2; ++ot) {
            f32x16 d = zero16();
#pragma unroll
            for (int kq = 0; kq < 4; ++kq)
                d = __builtin_amdgcn_mfma_f32_32x32x16_bf16(
                        __builtin_bit_cast(short8, tf[ot * 4 + kq]), fr[kq], d, 0, 0, 0);
#pragma unroll
            for (int r = 0; r < 16; ++r)
                acc[ot][r] += __builtin_fabsf(d[r]);
        }
    }

    // ---- 4-way icg merge (3 barriers), aliased on dead H ----
    float* P = (float*)H;
    __syncthreads();                              // everyone done reading H
    if (icg & 1) {                                // icg 1 -> p0, icg 3 -> p1
        const int rb = ((icg >> 1) * 2 + xh) * 2048;
#pragma unroll
        for (int ot = 0; ot < 2; ++ot)
#pragma unroll
            for (int rq = 0; rq < 4; ++rq)
                *(float4*)&P[rb + (ot * 4 + rq) * 256 + lane * 4] =
                    make_float4(acc[ot][rq * 4], acc[ot][rq * 4 + 1],
                                acc[ot][rq * 4 + 2], acc[ot][rq * 4 + 3]);
    }
    __syncthreads();
    if (!(icg & 1)) {                             // icg 0 absorbs p0, icg 2 p1
        const int rb = ((icg >> 1) * 2 + xh) * 2048;
#pragma unroll
        for (int ot = 0; ot < 2; ++ot)
#pragma unroll
            for (int rq = 0; rq < 4; ++rq)
#pragma unroll
                for (int i = 0; i < 4; ++i)
                    acc[ot][rq * 4 + i] += P[rb + (ot * 4 + rq) * 256 + lane * 4 + i];
    }
    if (icg == 2) {                               // publish sum to fresh p2
        const int rb = (4 + xh) * 2048;
#pragma unroll
        for (int ot = 0; ot < 2; ++ot)
#pragma unroll
            for (int rq = 0; rq < 4; ++rq)
                *(float4*)&P[rb + (ot * 4 + rq) * 256 + lane * 4] =
                    make_float4(acc[ot][rq * 4], acc[ot][rq * 4 + 1],
                                acc[ot][rq * 4 + 2], acc[ot][rq * 4 + 3]);
    }
    __syncthreads();
    if (icg == 0) {                               // final absorb + store
        const int rb = (4 + xh) * 2048;
#pragma unroll
        for (int ot = 0; ot < 2; ++ot)
#pragma unroll
            for (int reg = 0; reg < 16; ++reg) {
                const int oc = 32 * ot + (reg & 3) + 8 * (reg >> 2) + 4 * h;
                out[(size_t)(b * 64 + oc) * 4096 + y * 64 + xloc] =
                    acc[ot][reg] +
                    P[rb + (ot * 4 + (reg >> 2)) * 256 + lane * 4 + (reg & 3)];
            }
    }
}

} // namespace

extern "C" void kernel_launch(void* const* d_in, const int* in_sizes, int n_in,
                              void* d_out, int out_size, void* d_ws, size_t ws_size,
                              hipStream_t stream) {
    const float* img = (const float*)d_in[0];   // [8][32][64][64]
    const float* ker = (const float*)d_in[1];   // [64][32][7][7]
    float* out = (float*)d_out;                 // [8][64][64][64]
    uint4* B3 = (uint4*)d_ws;                   // 256 KB lane-major taps

    prep_B<<<dim3(64), dim3(256), 0, stream>>>(ker, B3);
    conv_mfma<<<dim3(512), dim3(512), 0, stream>>>(img, B3, out);
}

// Round 11
// 74.213 us; speedup vs baseline: 1.0113x; 1.0113x over previous
//
#include <hip/hip_runtime.h>

typedef __attribute__((ext_vector_type(8)))  short short8;
typedef __attribute__((ext_vector_type(16))) float f32x16;

namespace {

__device__ __forceinline__ unsigned short f2bf(float f) {
    unsigned int u = __float_as_uint(f);
    u += 0x7fffu + ((u >> 16) & 1u);     // RNE to bf16
    return (unsigned short)(u >> 16);
}

__device__ __forceinline__ f32x16 zero16() {
    f32x16 z;
#pragma unroll
    for (int r = 0; r < 16; ++r) z[r] = 0.0f;
    return z;
}

// ---------------------------------------------------------------------------
// B3: tap A-fragments for mfma_f32_32x32x16_bf16, lane-major coalesced.
// Index = ic*512 + (ot*4+kq)*64 + lane. Lane (m=lane&31, h=lane>>5) holds
// 8 bf16: taps q=0..7 (flipped, q==7 zero) of tap-row a = 2*kq+h (flipped;
// a==7 all-zero) for oc = 32*ot + m.
// ---------------------------------------------------------------------------
__global__ void prep_B(const float* __restrict__ ker, uint4* __restrict__ B3) {
    int t    = blockIdx.x * 256 + threadIdx.x;   // 16384 threads
    int lane = t & 63;
    int kq   = (t >> 6) & 3;
    int ot   = (t >> 8) & 1;
    int ic   = t >> 9;
    int m = lane & 31, h = lane >> 5;
    int oc = ot * 32 + m;
    int a  = 2 * kq + h;
    unsigned int d[4] = {0u, 0u, 0u, 0u};
    if (a < 7) {
        const float* row = ker + ((oc * 32 + ic) * 49) + (6 - a) * 7;
        float v[8];
#pragma unroll
        for (int q = 0; q < 7; ++q) v[q] = row[6 - q];
        v[7] = 0.0f;
#pragma unroll
        for (int j = 0; j < 4; ++j)
            d[j] = (unsigned int)f2bf(v[2 * j]) | ((unsigned int)f2bf(v[2 * j + 1]) << 16);
    }
    B3[t] = make_uint4(d[0], d[1], d[2], d[3]);
}

// ---------------------------------------------------------------------------
// Conv: grid 512 = b(8) x y(64), block 512 thr (8 waves) -> 2 blocks/CU.
// Wave w: xh = w&1 (32-px half), ot = (w>>1)&1 (32-oc half), ich = w>>2
// (16-ic half). Per ic: 4 tap loads (register double-buffered one ic AHEAD -
// MFMAs never wait on a fresh vmcnt), 4 img frags (stride-2 dwords), 4
// mfma_32x32x16, 16 fabs-adds; 16 uninterrupted ics. 2-way ich merge (scalar
// conflict-free LDS), 3 barriers total, plain coalesced stores.
// H (pitch 72, plane stride 504): dword p = pack(bf16 col (p-2)%64, (p-1)%64),
// rows r=0..6 = img rows (y-2+r)%64; kq==3 reads r=6 for both halves (h=1 is
// the all-zero a=7 tap row).
// ---------------------------------------------------------------------------
__global__ __launch_bounds__(512, 4) void conv_mfma(
    const float* __restrict__ img,          // [8][32][64][64]
    const uint4* __restrict__ B3,           // prepped taps
    float* __restrict__ out)                // [8][64][64][64]
{
    __shared__ unsigned int H[16128];       // 32*504 dwords = 63 KB

    const int bid  = blockIdx.x;            // b*64 + y
    const int y    = bid & 63;
    const int b    = bid >> 6;
    const int tid  = threadIdx.x;
    const int lane = tid & 63;
    const int w    = tid >> 6;              // 8 waves
    const int xh   = w & 1;
    const int ot   = (w >> 1) & 1;
    const int ich  = w >> 2;                // 0..1, 16 ic each
    const int n31  = lane & 31;
    const int h    = lane >> 5;

    const float* base = img + (size_t)b * 32 * 4096;

    // ---- stage: wave w owns planes 4w..4w+3, 7 rows each; col = lane ----
    float v[28];
#pragma unroll
    for (int j = 0; j < 28; ++j) {
        const int pl  = 4 * w + j / 7;
        const int row = (y - 2 + (j % 7)) & 63;
        v[j] = base[pl * 4096 + row * 64 + lane];
    }
#pragma unroll
    for (int j = 0; j < 28; ++j) {
        const int pl = 4 * w + j / 7;
        const int r  = j % 7;
        const unsigned int hh = f2bf(v[j]);
        const unsigned int hn = (unsigned int)__shfl((int)hh, (lane + 1) & 63);
        const unsigned int dw = hh | (hn << 16);  // cols (lane, lane+1) -> dword lane+2
        const int idx = pl * 504 + r * 72;
        H[idx + lane + 2] = dw;
        if (lane >= 62) H[idx + lane - 62] = dw;  // wrap left  (p = 0,1)
        if (lane <= 5)  H[idx + lane + 66] = dw;  // wrap right (p = 66..71)
    }
    __syncthreads();

    // ---- compute: 16 ic, taps double-buffered one ic ahead ----
    f32x16 acc = zero16();
    const int xloc = 32 * xh + n31;
    const int hv   = h * 72;
    const int ic0  = ich * 16;
    const int qb   = ot * 4;

    uint4 tfC[4], tfN[4];
#pragma unroll
    for (int kq = 0; kq < 4; ++kq)
        tfC[kq] = B3[ic0 * 512 + (qb + kq) * 64 + lane];

#pragma unroll
    for (int ici = 0; ici < 16; ++ici) {
        const int ic = ic0 + ici;
        if (ici < 15) {
#pragma unroll
            for (int kq = 0; kq < 4; ++kq)        // issue next ic's taps NOW
                tfN[kq] = B3[(ic + 1) * 512 + (qb + kq) * 64 + lane];
        }
        short8 fr[4];
#pragma unroll
        for (int kq = 0; kq < 4; ++kq) {
            const int ad = ic * 504 + ((kq < 3) ? (2 * kq * 72 + hv) : 432) + xloc;
            uint4 t4 = make_uint4(H[ad], H[ad + 2], H[ad + 4], H[ad + 6]);
            fr[kq] = __builtin_bit_cast(short8, t4);
        }
        f32x16 d = zero16();
#pragma unroll
        for (int kq = 0; kq < 4; ++kq)
            d = __builtin_amdgcn_mfma_f32_32x32x16_bf16(
                    __builtin_bit_cast(short8, tfC[kq]), fr[kq], d, 0, 0, 0);
#pragma unroll
        for (int r = 0; r < 16; ++r)
            acc[r] += __builtin_fabsf(d[r]);
#pragma unroll
        for (int kq = 0; kq < 4; ++kq) tfC[kq] = tfN[kq];   // renamed away
    }

    // ---- 2-way ich merge (conflict-free scalar dwords), then store ----
    float* P = (float*)H;                         // 4 regions of 1024 floats
    __syncthreads();                              // all compute done with H
    if (ich == 1) {
        const int rb = (xh * 2 + ot) * 1024;
#pragma unroll
        for (int r = 0; r < 16; ++r)
            P[rb + r * 64 + lane] = acc[r];
    }
    __syncthreads();
    if (ich == 0) {
        const int rb = (xh * 2 + ot) * 1024;
#pragma unroll
        for (int reg = 0; reg < 16; ++reg) {
            const int oc = 32 * ot + (reg & 3) + 8 * (reg >> 2) + 4 * h;
            out[(size_t)(b * 64 + oc) * 4096 + y * 64 + xloc] =
                acc[reg] + P[rb + reg * 64 + lane];
        }
    }
}

} // namespace

extern "C" void kernel_launch(void* const* d_in, const int* in_sizes, int n_in,
                              void* d_out, int out_size, void* d_ws, size_t ws_size,
                              hipStream_t stream) {
    const float* img = (const float*)d_in[0];   // [8][32][64][64]
    const float* ker = (const float*)d_in[1];   // [64][32][7][7]
    float* out = (float*)d_out;                 // [8][64][64][64]
    uint4* B3 = (uint4*)d_ws;                   // 256 KB lane-major taps

    prep_B<<<dim3(64), dim3(256), 0, stream>>>(ker, B3);
    conv_mfma<<<dim3(512), dim3(512), 0, stream>>>(img, B3, out);
}